// Round 3
// baseline (621.394 us; speedup 1.0000x reference)
//
#include <hip/hip_runtime.h>

typedef _Float16 half8 __attribute__((ext_vector_type(8)));
typedef _Float16 half4 __attribute__((ext_vector_type(4)));
typedef _Float16 half2v __attribute__((ext_vector_type(2)));
typedef float f4 __attribute__((ext_vector_type(4)));

// ---------------- graph preprocessing ----------------

__global__ void k_count(const int* __restrict__ ei, int E,
                        int* __restrict__ deg_src, int* __restrict__ cnt_dst) {
  int i = blockIdx.x * blockDim.x + threadIdx.x;
  if (i >= E) return;
  int dst = ei[i];        // edge_index[0] = row = destination
  int src = ei[E + i];    // edge_index[1] = col = source
  atomicAdd(&deg_src[src], 1);
  atomicAdd(&cnt_dst[dst], 1);
}

__global__ void k_dis(const int* __restrict__ deg_src, float* __restrict__ dis, int N) {
  int i = blockIdx.x * blockDim.x + threadIdx.x;
  if (i >= N) return;
  dis[i] = rsqrtf((float)(deg_src[i] + 1));
}

__global__ void k_scan1(const int* __restrict__ cnt, int* __restrict__ offs,
                        int* __restrict__ partial, int N) {
  __shared__ int s[1024];
  int t = threadIdx.x;
  int i = blockIdx.x * 1024 + t;
  int v = (i < N) ? cnt[i] : 0;
  s[t] = v;
  __syncthreads();
  for (int off = 1; off < 1024; off <<= 1) {
    int x = (t >= off) ? s[t - off] : 0;
    __syncthreads();
    s[t] += x;
    __syncthreads();
  }
  if (i < N) offs[i] = s[t] - v;
  if (t == 1023) partial[blockIdx.x] = s[1023];
}

__global__ void k_scan2(int* __restrict__ partial, int nb) {
  if (blockIdx.x == 0 && threadIdx.x == 0) {
    int run = 0;
    for (int j = 0; j < nb; ++j) { int tv = partial[j]; partial[j] = run; run += tv; }
  }
}

__global__ void k_scan3(int* __restrict__ offs, const int* __restrict__ partial,
                        int* __restrict__ cursor, int N, int E) {
  int t = threadIdx.x;
  int i = blockIdx.x * 1024 + t;
  if (i < N) {
    int o = offs[i] + partial[blockIdx.x];
    offs[i] = o;
    cursor[i] = o;
  }
  if (i == 0) offs[N] = E;
}

// XCD-partitioned scatter sort: each dst-range's srcs/cursor region is written
// (mostly) by blocks on ONE XCD, so 4B scatter writes merge to full lines in
// that XCD's L2 instead of partial-line HBM evictions (was 105MB WRITE_SIZE).
// XCC_ID is a locality HINT only: every block work-steals through all 8
// ranges, so coverage is exact regardless of block->XCD mapping.
#define SORT_CHUNK 4096

__global__ __launch_bounds__(256)
void k_sort2(const int* __restrict__ ei, int E, int N,
             int* __restrict__ cursor, int* __restrict__ srcs,
             int* __restrict__ work) {
  __shared__ int sc;
  int t = threadIdx.x;
  int myx;
  asm volatile("s_getreg_b32 %0, hwreg(HW_REG_XCC_ID)" : "=s"(myx));
  myx &= 7;
  int nchunks = (E + SORT_CHUNK - 1) / SORT_CHUNK;
  int per = (N + 7) / 8;
  for (int rr = 0; rr < 8; ++rr) {
    int r = (myx + rr) & 7;
    int lo = r * per;
    int hi = min(N, lo + per);
    for (;;) {
      if (t == 0) sc = atomicAdd(&work[r], 1);
      __syncthreads();
      int c = sc;
      __syncthreads();
      if (c >= nchunks) break;
      int base = c * SORT_CHUNK + t;
#pragma unroll
      for (int it = 0; it < 16; ++it) {
        int i = base + it * 256;
        if (i < E) {
          int dst = ei[i];
          if (dst >= lo && dst < hi) {
            int src = ei[E + i];
            int p = atomicAdd(&cursor[dst], 1);
            srcs[p] = src;
          }
        }
      }
    }
  }
}

// W (128x128 fp32 row-major, W[k][c]) -> Wt fp16 transposed: Wt[c][k]
__global__ void k_prepw(const float* __restrict__ W0, const float* __restrict__ W1,
                        const float* __restrict__ W2, _Float16* __restrict__ Wt) {
  int i = blockIdx.x * blockDim.x + threadIdx.x;   // 0..49151
  int m = i >> 14;
  int j = i & 16383;
  int c = j >> 7, k = j & 127;
  const float* W = (m == 0) ? W0 : (m == 1) ? W1 : W2;
  Wt[i] = (_Float16)W[k * 128 + c];
}

// ---------------- fp16 MFMA GEMM + dis-scale epilogue ----------------
// hws[r][:] = dis[r] * (relu?(in[r][:]) @ W)  as fp16.
// Swapped operands: A = W^T (M-dim = W cols), B = h^T (N-dim = h rows).

#define LDH 136   // padded halves per row (272 B) -> conflict-free ds_read_b128

__global__ __launch_bounds__(256, 2)
void k_gemm(const float* __restrict__ in, int in_stride, int do_relu,
            const _Float16* __restrict__ Wt_g, const float* __restrict__ dis,
            _Float16* __restrict__ hws, int N) {
  __shared__ _Float16 Wt[128 * LDH];
  int t = threadIdx.x;
  int rbase = blockIdx.x * 128;

#pragma unroll
  for (int i = 0; i < 8; ++i) {
    int s = t + i * 256;
    int c = s >> 4, kh = s & 15;
    half8 w = ((const half8*)Wt_g)[s];
    *(half8*)&Wt[c * LDH + kh * 8] = w;
  }
  __syncthreads();

  int wv = t >> 6, lane = t & 63;
  int r0 = wv * 32;
  int lr = lane & 15, lg = lane >> 4;

  f4 acc[2][8];
#pragma unroll
  for (int fm = 0; fm < 2; ++fm)
#pragma unroll
    for (int fn = 0; fn < 8; ++fn) acc[fm][fn] = (f4){0.f, 0.f, 0.f, 0.f};

#pragma unroll
  for (int ks = 0; ks < 4; ++ks) {
    int k0 = ks * 32 + lg * 8;
    half8 a[8];
#pragma unroll
    for (int fn = 0; fn < 8; ++fn)
      a[fn] = *(const half8*)&Wt[(fn * 16 + lr) * LDH + k0];
#pragma unroll
    for (int fm = 0; fm < 2; ++fm) {
      int gr = rbase + r0 + fm * 16 + lr;
      float4 v0 = make_float4(0.f, 0.f, 0.f, 0.f);
      float4 v1 = make_float4(0.f, 0.f, 0.f, 0.f);
      if (gr < N) {
        const float* pr = in + (size_t)gr * in_stride + k0;
        v0 = *(const float4*)pr;
        v1 = *(const float4*)(pr + 4);
      }
      if (do_relu) {
        v0.x = fmaxf(v0.x, 0.f); v0.y = fmaxf(v0.y, 0.f);
        v0.z = fmaxf(v0.z, 0.f); v0.w = fmaxf(v0.w, 0.f);
        v1.x = fmaxf(v1.x, 0.f); v1.y = fmaxf(v1.y, 0.f);
        v1.z = fmaxf(v1.z, 0.f); v1.w = fmaxf(v1.w, 0.f);
      }
      half8 b;
      b[0] = (_Float16)v0.x; b[1] = (_Float16)v0.y;
      b[2] = (_Float16)v0.z; b[3] = (_Float16)v0.w;
      b[4] = (_Float16)v1.x; b[5] = (_Float16)v1.y;
      b[6] = (_Float16)v1.z; b[7] = (_Float16)v1.w;
#pragma unroll
      for (int fn = 0; fn < 8; ++fn)
        acc[fm][fn] = __builtin_amdgcn_mfma_f32_16x16x32_f16(a[fn], b, acc[fm][fn], 0, 0, 0);
    }
  }

#pragma unroll
  for (int fm = 0; fm < 2; ++fm) {
    int gr = rbase + r0 + fm * 16 + lr;
    if (gr >= N) continue;
    float dv = dis[gr];
#pragma unroll
    for (int fn = 0; fn < 8; ++fn) {
      f4 d = acc[fm][fn];
      half4 hv;
      hv[0] = (_Float16)(d[0] * dv);
      hv[1] = (_Float16)(d[1] * dv);
      hv[2] = (_Float16)(d[2] * dv);
      hv[3] = (_Float16)(d[3] * dv);
      *(half4*)(hws + (size_t)gr * 128 + fn * 16 + lg * 4) = hv;
    }
  }
}

// ---------------- aggregation: wave/node, fp16 gathers, 8-deep MLP ----------------

__global__ __launch_bounds__(256)
void k_agg(const _Float16* __restrict__ hws, const int* __restrict__ offs,
           const int* __restrict__ srcs, const float* __restrict__ dis,
           const float* __restrict__ bias, float* __restrict__ out,
           int N, int layer) {
  int wv = threadIdx.x >> 6, lane = threadIdx.x & 63;
  int v = blockIdx.x * 4 + wv;
  if (v >= N) return;

  const uint* h32 = (const uint*)hws;
  uint hv = h32[(size_t)v * 64 + lane];
  half2v h = __builtin_bit_cast(half2v, hv);
  float ax = (float)h[0], ay = (float)h[1];

  int e0 = offs[v], e1 = offs[v + 1];
  int e = e0;
  for (; e + 8 <= e1; e += 8) {
    int s0 = srcs[e + 0], s1 = srcs[e + 1], s2 = srcs[e + 2], s3 = srcs[e + 3];
    int s4 = srcs[e + 4], s5 = srcs[e + 5], s6 = srcs[e + 6], s7 = srcs[e + 7];
    uint u0 = h32[(size_t)s0 * 64 + lane];
    uint u1 = h32[(size_t)s1 * 64 + lane];
    uint u2 = h32[(size_t)s2 * 64 + lane];
    uint u3 = h32[(size_t)s3 * 64 + lane];
    uint u4 = h32[(size_t)s4 * 64 + lane];
    uint u5 = h32[(size_t)s5 * 64 + lane];
    uint u6 = h32[(size_t)s6 * 64 + lane];
    uint u7 = h32[(size_t)s7 * 64 + lane];
    half2v p0 = __builtin_bit_cast(half2v, u0);
    half2v p1 = __builtin_bit_cast(half2v, u1);
    half2v p2 = __builtin_bit_cast(half2v, u2);
    half2v p3 = __builtin_bit_cast(half2v, u3);
    half2v p4 = __builtin_bit_cast(half2v, u4);
    half2v p5 = __builtin_bit_cast(half2v, u5);
    half2v p6 = __builtin_bit_cast(half2v, u6);
    half2v p7 = __builtin_bit_cast(half2v, u7);
    ax += (float)p0[0] + (float)p1[0] + (float)p2[0] + (float)p3[0]
        + (float)p4[0] + (float)p5[0] + (float)p6[0] + (float)p7[0];
    ay += (float)p0[1] + (float)p1[1] + (float)p2[1] + (float)p3[1]
        + (float)p4[1] + (float)p5[1] + (float)p6[1] + (float)p7[1];
  }
  for (; e < e1; ++e) {
    int s = srcs[e];
    uint u = h32[(size_t)s * 64 + lane];
    half2v p = __builtin_bit_cast(half2v, u);
    ax += (float)p[0];
    ay += (float)p[1];
  }

  float dv = dis[v];
  float2 b = ((const float2*)bias)[lane];
  float2 o;
  o.x = fmaf(dv, ax, b.x);
  o.y = fmaf(dv, ay, b.y);
  *(float2*)(out + (size_t)v * 384 + layer * 128 + 2 * lane) = o;
}

// ---------------- launch ----------------

extern "C" void kernel_launch(void* const* d_in, const int* in_sizes, int n_in,
                              void* d_out, int out_size, void* d_ws, size_t ws_size,
                              hipStream_t stream) {
  const float* x  = (const float*)d_in[0];
  const int*   ei = (const int*)d_in[1];
  const float* W0 = (const float*)d_in[2];
  const float* b0 = (const float*)d_in[3];
  const float* W1 = (const float*)d_in[4];
  const float* b1 = (const float*)d_in[5];
  const float* W2 = (const float*)d_in[6];
  const float* b2 = (const float*)d_in[7];
  float* out = (float*)d_out;

  int N = in_sizes[0] / 128;
  int E = in_sizes[1] / 2;

  char* p = (char*)d_ws;
  auto alloc = [&](size_t sz) { char* r = p; p += (sz + 255) & ~(size_t)255; return r; };
  _Float16* hws  = (_Float16*)alloc((size_t)N * 128 * 2);
  float* dis     = (float*)alloc((size_t)N * 4);
  int*   deg     = (int*)alloc((size_t)N * 4);
  int*   cnt     = (int*)alloc((size_t)N * 4);
  int*   offs    = (int*)alloc((size_t)(N + 1) * 4);
  int*   cursor  = (int*)alloc((size_t)N * 4);
  int*   srcs    = (int*)alloc((size_t)E * 4);
  int*   partial = (int*)alloc(1024 * 4);
  _Float16* Wt   = (_Float16*)alloc((size_t)3 * 128 * 128 * 2);
  int*   work    = (int*)alloc(64);

  hipMemsetAsync(deg, 0, (size_t)N * 4, stream);
  hipMemsetAsync(cnt, 0, (size_t)N * 4, stream);
  hipMemsetAsync(work, 0, 64, stream);

  int gE = (E + 255) / 256;
  int nch = (N + 1023) / 1024;
  k_count<<<gE, 256, 0, stream>>>(ei, E, deg, cnt);
  k_dis<<<(N + 255) / 256, 256, 0, stream>>>(deg, dis, N);
  k_scan1<<<nch, 1024, 0, stream>>>(cnt, offs, partial, N);
  k_scan2<<<1, 64, 0, stream>>>(partial, nch);
  k_scan3<<<nch, 1024, 0, stream>>>(offs, partial, cursor, N, E);
  k_sort2<<<1024, 256, 0, stream>>>(ei, E, N, cursor, srcs, work);
  k_prepw<<<192, 256, 0, stream>>>(W0, W1, W2, Wt);

  int gG = (N + 127) / 128;
  int gA = (N + 3) / 4;

  // layer 0
  k_gemm<<<gG, 256, 0, stream>>>(x, 128, 0, Wt, dis, hws, N);
  k_agg<<<gA, 256, 0, stream>>>(hws, offs, srcs, dis, b0, out, N, 0);
  // layer 1: input = relu(out[:,0,:]) (stride 384)
  k_gemm<<<gG, 256, 0, stream>>>(out, 384, 1, Wt + 16384, dis, hws, N);
  k_agg<<<gA, 256, 0, stream>>>(hws, offs, srcs, dis, b1, out, N, 1);
  // layer 2: input = relu(out[:,1,:])
  k_gemm<<<gG, 256, 0, stream>>>(out + 128, 384, 1, Wt + 32768, dis, hws, N);
  k_agg<<<gA, 256, 0, stream>>>(hws, offs, srcs, dis, b2, out, N, 2);
}

// Round 5
// 572.140 us; speedup vs baseline: 1.0861x; 1.0861x over previous
//
#include <hip/hip_runtime.h>

typedef _Float16 half8 __attribute__((ext_vector_type(8)));
typedef _Float16 half4 __attribute__((ext_vector_type(4)));
typedef _Float16 half2v __attribute__((ext_vector_type(2)));
typedef float f4 __attribute__((ext_vector_type(4)));

#define NBMAX 1024        // coarse buckets (256 dst nodes each), supports N<=262144

// ---------------- graph preprocessing ----------------

// degrees + per-dst counts + coarse bucket histogram (LDS-aggregated)
__global__ __launch_bounds__(256)
void k_count(const int* __restrict__ ei, int E,
             int* __restrict__ deg_src, int* __restrict__ cnt_dst,
             int* __restrict__ bcnt) {
  __shared__ int h[NBMAX];
  for (int i = threadIdx.x; i < NBMAX; i += 256) h[i] = 0;
  __syncthreads();
  int stride = gridDim.x * blockDim.x;
  for (int i = blockIdx.x * blockDim.x + threadIdx.x; i < E; i += stride) {
    int dst = __builtin_nontemporal_load(&ei[i]);
    int src = __builtin_nontemporal_load(&ei[E + i]);
    atomicAdd(&deg_src[src], 1);
    atomicAdd(&cnt_dst[dst], 1);
    atomicAdd(&h[dst >> 8], 1);
  }
  __syncthreads();
  for (int b = threadIdx.x; b < NBMAX; b += 256)
    if (h[b]) atomicAdd(&bcnt[b], h[b]);
}

__global__ void k_dis(const int* __restrict__ deg_src, float* __restrict__ dis, int N) {
  int i = blockIdx.x * blockDim.x + threadIdx.x;
  if (i >= N) return;
  dis[i] = rsqrtf((float)(deg_src[i] + 1));
}

__global__ void k_scan1(const int* __restrict__ cnt, int* __restrict__ offs,
                        int* __restrict__ partial, int N) {
  __shared__ int s[1024];
  int t = threadIdx.x;
  int i = blockIdx.x * 1024 + t;
  int v = (i < N) ? cnt[i] : 0;
  s[t] = v;
  __syncthreads();
  for (int off = 1; off < 1024; off <<= 1) {
    int x = (t >= off) ? s[t - off] : 0;
    __syncthreads();
    s[t] += x;
    __syncthreads();
  }
  if (i < N) offs[i] = s[t] - v;
  if (t == 1023) partial[blockIdx.x] = s[1023];
}

__global__ void k_scan2(int* __restrict__ partial, int nb) {
  if (blockIdx.x == 0 && threadIdx.x == 0) {
    int run = 0;
    for (int j = 0; j < nb; ++j) { int tv = partial[j]; partial[j] = run; run += tv; }
  }
}

__global__ void k_scan3(int* __restrict__ offs, const int* __restrict__ partial,
                        int* __restrict__ cursor, int N, int E) {
  int t = threadIdx.x;
  int i = blockIdx.x * 1024 + t;
  if (i < N) {
    int o = offs[i] + partial[blockIdx.x];
    offs[i] = o;
    cursor[i] = o;
  }
  if (i == 0) offs[N] = E;
}

// serial scan over coarse buckets (nb ~ 391)
__global__ void k_bscan(const int* __restrict__ bcnt, int* __restrict__ boffs,
                        int* __restrict__ bcur, int nb) {
  if (blockIdx.x == 0 && threadIdx.x == 0) {
    int run = 0;
    for (int b = 0; b < nb; ++b) { boffs[b] = run; bcur[b] = run; run += bcnt[b]; }
    boffs[nb] = run;
  }
}

// coarse scatter: edges -> bucket-grouped (dst,src) packed u64. Per-block LDS
// hist, one range-reservation atomic per (block,bucket), then contiguous runs
// per bucket -> L2-mergeable full-line writes.
#define CS_CHUNK 8192
__global__ __launch_bounds__(256)
void k_bscatter(const int* __restrict__ ei, int E,
                int* __restrict__ bcur, unsigned long long* __restrict__ pairs) {
  __shared__ int h[NBMAX];
  __shared__ int basearr[NBMAX];
  int t = threadIdx.x;
  for (int i = t; i < NBMAX; i += 256) h[i] = 0;
  __syncthreads();
  int base = blockIdx.x * CS_CHUNK;
  int end = min(E, base + CS_CHUNK);
  for (int i = base + t; i < end; i += 256) {
    int dst = __builtin_nontemporal_load(&ei[i]);
    atomicAdd(&h[dst >> 8], 1);
  }
  __syncthreads();
  for (int b = t; b < NBMAX; b += 256) {
    int n = h[b];
    if (n) basearr[b] = atomicAdd(&bcur[b], n);
    h[b] = 0;
  }
  __syncthreads();
  for (int i = base + t; i < end; i += 256) {
    int dst = __builtin_nontemporal_load(&ei[i]);
    int src = __builtin_nontemporal_load(&ei[E + i]);
    int b = dst >> 8;
    int pos = atomicAdd(&h[b], 1);
    unsigned long long pk = ((unsigned long long)(unsigned)src << 32) | (unsigned)dst;
    pairs[basearr[b] + pos] = pk;
  }
}

// fine scatter: one block per bucket; cursor (1KB) + srcs (~16KB) region is
// owned by this block for its whole lifetime -> full L2 write merging.
__global__ __launch_bounds__(256)
void k_fscatter(const unsigned long long* __restrict__ pairs,
                const int* __restrict__ boffs,
                int* __restrict__ cursor, int* __restrict__ srcs) {
  int b = blockIdx.x;
  int lo = boffs[b], hi = boffs[b + 1];
  for (int i = lo + threadIdx.x; i < hi; i += 256) {
    unsigned long long pk = __builtin_nontemporal_load(&pairs[i]);
    int dst = (int)(unsigned)(pk & 0xffffffffull);
    int src = (int)(unsigned)(pk >> 32);
    int p = atomicAdd(&cursor[dst], 1);
    srcs[p] = src;
  }
}

// W (128x128 fp32 row-major, W[k][c]) -> Wt fp16 transposed: Wt[c][k]
__global__ void k_prepw(const float* __restrict__ W0, const float* __restrict__ W1,
                        const float* __restrict__ W2, _Float16* __restrict__ Wt) {
  int i = blockIdx.x * blockDim.x + threadIdx.x;   // 0..49151
  int m = i >> 14;
  int j = i & 16383;
  int c = j >> 7, k = j & 127;
  const float* W = (m == 0) ? W0 : (m == 1) ? W1 : W2;
  Wt[i] = (_Float16)W[k * 128 + c];
}

// ---------------- fp16 MFMA GEMM + dis-scale epilogue ----------------
// hws[r][:] = dis[r] * (relu?(in[r][:]) @ W)  as fp16.

#define LDH 136   // padded halves per row -> conflict-free ds_read_b128

__global__ __launch_bounds__(256, 2)
void k_gemm(const float* __restrict__ in, int in_stride, int do_relu,
            const _Float16* __restrict__ Wt_g, const float* __restrict__ dis,
            _Float16* __restrict__ hws, int N) {
  __shared__ _Float16 Wt[128 * LDH];
  int t = threadIdx.x;
  int rbase = blockIdx.x * 128;

#pragma unroll
  for (int i = 0; i < 8; ++i) {
    int s = t + i * 256;
    int c = s >> 4, kh = s & 15;
    half8 w = ((const half8*)Wt_g)[s];
    *(half8*)&Wt[c * LDH + kh * 8] = w;
  }
  __syncthreads();

  int wv = t >> 6, lane = t & 63;
  int r0 = wv * 32;
  int lr = lane & 15, lg = lane >> 4;

  f4 acc[2][8];
#pragma unroll
  for (int fm = 0; fm < 2; ++fm)
#pragma unroll
    for (int fn = 0; fn < 8; ++fn) acc[fm][fn] = (f4){0.f, 0.f, 0.f, 0.f};

#pragma unroll
  for (int ks = 0; ks < 4; ++ks) {
    int k0 = ks * 32 + lg * 8;
    half8 a[8];
#pragma unroll
    for (int fn = 0; fn < 8; ++fn)
      a[fn] = *(const half8*)&Wt[(fn * 16 + lr) * LDH + k0];
#pragma unroll
    for (int fm = 0; fm < 2; ++fm) {
      int gr = rbase + r0 + fm * 16 + lr;
      float4 v0 = make_float4(0.f, 0.f, 0.f, 0.f);
      float4 v1 = make_float4(0.f, 0.f, 0.f, 0.f);
      if (gr < N) {
        const float* pr = in + (size_t)gr * in_stride + k0;
        v0 = *(const float4*)pr;
        v1 = *(const float4*)(pr + 4);
      }
      if (do_relu) {
        v0.x = fmaxf(v0.x, 0.f); v0.y = fmaxf(v0.y, 0.f);
        v0.z = fmaxf(v0.z, 0.f); v0.w = fmaxf(v0.w, 0.f);
        v1.x = fmaxf(v1.x, 0.f); v1.y = fmaxf(v1.y, 0.f);
        v1.z = fmaxf(v1.z, 0.f); v1.w = fmaxf(v1.w, 0.f);
      }
      half8 b;
      b[0] = (_Float16)v0.x; b[1] = (_Float16)v0.y;
      b[2] = (_Float16)v0.z; b[3] = (_Float16)v0.w;
      b[4] = (_Float16)v1.x; b[5] = (_Float16)v1.y;
      b[6] = (_Float16)v1.z; b[7] = (_Float16)v1.w;
#pragma unroll
      for (int fn = 0; fn < 8; ++fn)
        acc[fm][fn] = __builtin_amdgcn_mfma_f32_16x16x32_f16(a[fn], b, acc[fm][fn], 0, 0, 0);
    }
  }

#pragma unroll
  for (int fm = 0; fm < 2; ++fm) {
    int gr = rbase + r0 + fm * 16 + lr;
    if (gr >= N) continue;
    float dv = dis[gr];
#pragma unroll
    for (int fn = 0; fn < 8; ++fn) {
      f4 d = acc[fm][fn];
      half4 hv;
      hv[0] = (_Float16)(d[0] * dv);
      hv[1] = (_Float16)(d[1] * dv);
      hv[2] = (_Float16)(d[2] * dv);
      hv[3] = (_Float16)(d[3] * dv);
      *(half4*)(hws + (size_t)gr * 128 + fn * 16 + lg * 4) = hv;
    }
  }
}

// ---------------- aggregation: wave/node, fp16 gathers, 8-deep MLP ----------------

__global__ __launch_bounds__(256)
void k_agg(const _Float16* __restrict__ hws, const int* __restrict__ offs,
           const int* __restrict__ srcs, const float* __restrict__ dis,
           const float* __restrict__ bias, float* __restrict__ out,
           int N, int layer) {
  int wv = threadIdx.x >> 6, lane = threadIdx.x & 63;
  int v = blockIdx.x * 4 + wv;
  if (v >= N) return;

  const uint* h32 = (const uint*)hws;
  uint hv = h32[(size_t)v * 64 + lane];
  half2v h = __builtin_bit_cast(half2v, hv);
  float ax = (float)h[0], ay = (float)h[1];

  int e0 = offs[v], e1 = offs[v + 1];
  int e = e0;
  for (; e + 8 <= e1; e += 8) {
    int s0 = srcs[e + 0], s1 = srcs[e + 1], s2 = srcs[e + 2], s3 = srcs[e + 3];
    int s4 = srcs[e + 4], s5 = srcs[e + 5], s6 = srcs[e + 6], s7 = srcs[e + 7];
    uint u0 = h32[(size_t)s0 * 64 + lane];
    uint u1 = h32[(size_t)s1 * 64 + lane];
    uint u2 = h32[(size_t)s2 * 64 + lane];
    uint u3 = h32[(size_t)s3 * 64 + lane];
    uint u4 = h32[(size_t)s4 * 64 + lane];
    uint u5 = h32[(size_t)s5 * 64 + lane];
    uint u6 = h32[(size_t)s6 * 64 + lane];
    uint u7 = h32[(size_t)s7 * 64 + lane];
    half2v p0 = __builtin_bit_cast(half2v, u0);
    half2v p1 = __builtin_bit_cast(half2v, u1);
    half2v p2 = __builtin_bit_cast(half2v, u2);
    half2v p3 = __builtin_bit_cast(half2v, u3);
    half2v p4 = __builtin_bit_cast(half2v, u4);
    half2v p5 = __builtin_bit_cast(half2v, u5);
    half2v p6 = __builtin_bit_cast(half2v, u6);
    half2v p7 = __builtin_bit_cast(half2v, u7);
    ax += (float)p0[0] + (float)p1[0] + (float)p2[0] + (float)p3[0]
        + (float)p4[0] + (float)p5[0] + (float)p6[0] + (float)p7[0];
    ay += (float)p0[1] + (float)p1[1] + (float)p2[1] + (float)p3[1]
        + (float)p4[1] + (float)p5[1] + (float)p6[1] + (float)p7[1];
  }
  for (; e < e1; ++e) {
    int s = srcs[e];
    uint u = h32[(size_t)s * 64 + lane];
    half2v p = __builtin_bit_cast(half2v, u);
    ax += (float)p[0];
    ay += (float)p[1];
  }

  float dv = dis[v];
  float2 b = ((const float2*)bias)[lane];
  float2 o;
  o.x = fmaf(dv, ax, b.x);
  o.y = fmaf(dv, ay, b.y);
  *(float2*)(out + (size_t)v * 384 + layer * 128 + 2 * lane) = o;
}

// ---------------- launch ----------------

extern "C" void kernel_launch(void* const* d_in, const int* in_sizes, int n_in,
                              void* d_out, int out_size, void* d_ws, size_t ws_size,
                              hipStream_t stream) {
  const float* x  = (const float*)d_in[0];
  const int*   ei = (const int*)d_in[1];
  const float* W0 = (const float*)d_in[2];
  const float* b0 = (const float*)d_in[3];
  const float* W1 = (const float*)d_in[4];
  const float* b1 = (const float*)d_in[5];
  const float* W2 = (const float*)d_in[6];
  const float* b2 = (const float*)d_in[7];
  float* out = (float*)d_out;

  int N = in_sizes[0] / 128;
  int E = in_sizes[1] / 2;
  int nb = (N + 255) >> 8;                 // coarse buckets

  char* p = (char*)d_ws;
  auto alloc = [&](size_t sz) { char* r = p; p += (sz + 255) & ~(size_t)255; return r; };
  _Float16* hws  = (_Float16*)alloc((size_t)N * 128 * 2);
  float* dis     = (float*)alloc((size_t)N * 4);
  int*   deg     = (int*)alloc((size_t)N * 4);
  int*   cnt     = (int*)alloc((size_t)N * 4);
  int*   offs    = (int*)alloc((size_t)(N + 1) * 4);
  int*   cursor  = (int*)alloc((size_t)N * 4);
  int*   srcs    = (int*)alloc((size_t)E * 4);
  int*   partial = (int*)alloc(1024 * 4);
  _Float16* Wt   = (_Float16*)alloc((size_t)3 * 128 * 128 * 2);
  int*   bcnt    = (int*)alloc((size_t)NBMAX * 4);
  int*   boffs   = (int*)alloc((size_t)(NBMAX + 1) * 4);
  int*   bcur    = (int*)alloc((size_t)NBMAX * 4);
  unsigned long long* pairs = (unsigned long long*)alloc((size_t)E * 8);

  hipMemsetAsync(deg, 0, (size_t)N * 4, stream);
  hipMemsetAsync(cnt, 0, (size_t)N * 4, stream);
  hipMemsetAsync(bcnt, 0, (size_t)NBMAX * 4, stream);

  int nch = (N + 1023) / 1024;
  k_count<<<2048, 256, 0, stream>>>(ei, E, deg, cnt, bcnt);
  k_dis<<<(N + 255) / 256, 256, 0, stream>>>(deg, dis, N);
  k_scan1<<<nch, 1024, 0, stream>>>(cnt, offs, partial, N);
  k_scan2<<<1, 64, 0, stream>>>(partial, nch);
  k_scan3<<<nch, 1024, 0, stream>>>(offs, partial, cursor, N, E);
  k_bscan<<<1, 64, 0, stream>>>(bcnt, boffs, bcur, nb);
  int gB = (E + CS_CHUNK - 1) / CS_CHUNK;
  k_bscatter<<<gB, 256, 0, stream>>>(ei, E, bcur, pairs);
  k_fscatter<<<nb, 256, 0, stream>>>(pairs, boffs, cursor, srcs);
  k_prepw<<<192, 256, 0, stream>>>(W0, W1, W2, Wt);

  int gG = (N + 127) / 128;
  int gA = (N + 3) / 4;

  // layer 0
  k_gemm<<<gG, 256, 0, stream>>>(x, 128, 0, Wt, dis, hws, N);
  k_agg<<<gA, 256, 0, stream>>>(hws, offs, srcs, dis, b0, out, N, 0);
  // layer 1: input = relu(out[:,0,:]) (stride 384)
  k_gemm<<<gG, 256, 0, stream>>>(out, 384, 1, Wt + 16384, dis, hws, N);
  k_agg<<<gA, 256, 0, stream>>>(hws, offs, srcs, dis, b1, out, N, 1);
  // layer 2: input = relu(out[:,1,:])
  k_gemm<<<gG, 256, 0, stream>>>(out + 128, 384, 1, Wt + 32768, dis, hws, N);
  k_agg<<<gA, 256, 0, stream>>>(hws, offs, srcs, dis, b2, out, N, 2);
}

// Round 6
// 384.538 us; speedup vs baseline: 1.6160x; 1.4879x over previous
//
#include <hip/hip_runtime.h>

typedef _Float16 half8 __attribute__((ext_vector_type(8)));
typedef _Float16 half4 __attribute__((ext_vector_type(4)));
typedef _Float16 half2v __attribute__((ext_vector_type(2)));
typedef float f4 __attribute__((ext_vector_type(4)));

#define NBK 1024     // bucket table size (256 nodes/bucket, supports N<=262144)
#define NBLK 128     // blocks in hist/scatter passes (fixed edge chunking)

// ---------------- graph preprocessing (NO global atomics) ----------------

// per-block LDS histograms of dst-bucket and src-bucket; private rows out.
__global__ __launch_bounds__(256)
void k_bhist(const int* __restrict__ ei, int E, int chunk,
             int* __restrict__ hb) {
  __shared__ int hd[NBK], hs[NBK];
  int t = threadIdx.x, blk = blockIdx.x;
  for (int i = t; i < NBK; i += 256) { hd[i] = 0; hs[i] = 0; }
  __syncthreads();
  int start = blk * chunk, end = min(E, start + chunk);
  for (int i = start + t; i < end; i += 256) {
    int dst = ei[i];
    int src = ei[E + i];
    atomicAdd(&hd[dst >> 8], 1);
    atomicAdd(&hs[src >> 8], 1);
  }
  __syncthreads();
  for (int i = t; i < NBK; i += 256) {
    hb[blk * NBK + i] = hd[i];
    hb[(NBLK + blk) * NBK + i] = hs[i];
  }
}

// column-wise exclusive scan over blocks (both tables); totals per bucket.
// thread tid -> (table, bucket); reads are coalesced across consecutive j.
__global__ void k_colscan(int* __restrict__ hb, int* __restrict__ totals) {
  int tid = blockIdx.x * 256 + threadIdx.x;      // 0..2047
  int* tab = hb + (tid >> 10) * (NBLK * NBK);
  int j = tid & (NBK - 1);
  int run = 0;
  for (int b = 0; b < NBLK; ++b) {
    int idx = b * NBK + j;
    int v = tab[idx];
    tab[idx] = run;
    run += v;
  }
  totals[tid] = run;
}

// single-block scans of bucket totals -> boffs (pairs) and soffs (src bytes)
__global__ void k_bscan2(const int* __restrict__ totals, int* __restrict__ boffs,
                         int* __restrict__ soffs, int* __restrict__ offs,
                         int N, int E) {
  __shared__ int s[NBK];
  int t = threadIdx.x;                            // 1024 threads
  int v = totals[t];
  s[t] = v;
  __syncthreads();
  for (int off = 1; off < NBK; off <<= 1) {
    int x = (t >= off) ? s[t - off] : 0;
    __syncthreads();
    s[t] += x;
    __syncthreads();
  }
  boffs[t] = s[t] - v;
  if (t == NBK - 1) boffs[NBK] = s[t];
  __syncthreads();
  int v2 = totals[NBK + t];
  s[t] = v2;
  __syncthreads();
  for (int off = 1; off < NBK; off <<= 1) {
    int x = (t >= off) ? s[t - off] : 0;
    __syncthreads();
    s[t] += x;
    __syncthreads();
  }
  soffs[t] = s[t] - v2;
  if (t == NBK - 1) soffs[NBK] = s[t];
  if (t == 0) offs[N] = E;
}

// scatter edges into dst-bucketed u64 pairs + src-bucketed byte stream,
// at pre-reserved per-(block,bucket) ranges with LDS cursors.
__global__ __launch_bounds__(256)
void k_bscatter(const int* __restrict__ ei, int E, int chunk,
                const int* __restrict__ hb, const int* __restrict__ boffs,
                const int* __restrict__ soffs,
                unsigned long long* __restrict__ pairs,
                unsigned char* __restrict__ srcb) {
  __shared__ int based[NBK], posd[NBK], bases[NBK], poss[NBK];
  int t = threadIdx.x, blk = blockIdx.x;
  for (int i = t; i < NBK; i += 256) {
    based[i] = hb[blk * NBK + i] + boffs[i];
    posd[i] = 0;
    bases[i] = hb[(NBLK + blk) * NBK + i] + soffs[i];
    poss[i] = 0;
  }
  __syncthreads();
  int start = blk * chunk, end = min(E, start + chunk);
  for (int i = start + t; i < end; i += 256) {
    int dst = ei[i];
    int src = ei[E + i];
    int bd = dst >> 8, bs = src >> 8;
    int p = atomicAdd(&posd[bd], 1);
    pairs[based[bd] + p] =
        ((unsigned long long)(unsigned)src << 32) | (unsigned)dst;
    int q = atomicAdd(&poss[bs], 1);
    srcb[bases[bs] + q] = (unsigned char)(src & 255);
  }
}

// one block per src-bucket: LDS histogram of byte stream -> dis (coalesced)
__global__ __launch_bounds__(256)
void k_deg(const unsigned char* __restrict__ srcb, const int* __restrict__ soffs,
           float* __restrict__ dis, int N) {
  __shared__ int h[256];
  int b = blockIdx.x, t = threadIdx.x;
  h[t] = 0;
  __syncthreads();
  int lo = soffs[b], hi = soffs[b + 1];
  for (int i = lo + t; i < hi; i += 256) atomicAdd(&h[srcb[i]], 1);
  __syncthreads();
  int v = (b << 8) + t;
  if (v < N) dis[v] = rsqrtf((float)(h[t] + 1));
}

// one block per dst-bucket: LDS hist + scan -> offs; LDS-cursor scatter -> srcs.
// All srcs writes confined to this block's private [pl,ph) region.
__global__ __launch_bounds__(256)
void k_fscatter(const unsigned long long* __restrict__ pairs,
                const int* __restrict__ boffs,
                int* __restrict__ offs, int* __restrict__ srcs, int N) {
  __shared__ int h[256], sc[256], cur[256];
  int b = blockIdx.x, t = threadIdx.x;
  h[t] = 0;
  __syncthreads();
  int pl = boffs[b], ph = boffs[b + 1];
  for (int i = pl + t; i < ph; i += 256)
    atomicAdd(&h[(int)(pairs[i] & 255ull)], 1);
  __syncthreads();
  sc[t] = h[t];
  __syncthreads();
  for (int off = 1; off < 256; off <<= 1) {
    int x = (t >= off) ? sc[t - off] : 0;
    __syncthreads();
    sc[t] += x;
    __syncthreads();
  }
  int excl = sc[t] - h[t];
  int v = (b << 8) + t;
  if (v < N) offs[v] = pl + excl;
  cur[t] = pl + excl;
  __syncthreads();
  for (int i = pl + t; i < ph; i += 256) {
    unsigned long long pk = pairs[i];
    int p = atomicAdd(&cur[(int)(pk & 255ull)], 1);
    srcs[p] = (int)(unsigned)(pk >> 32);
  }
}

// W (128x128 fp32 row-major, W[k][c]) -> Wt fp16 transposed: Wt[c][k]
__global__ void k_prepw(const float* __restrict__ W0, const float* __restrict__ W1,
                        const float* __restrict__ W2, _Float16* __restrict__ Wt) {
  int i = blockIdx.x * blockDim.x + threadIdx.x;   // 0..49151
  int m = i >> 14;
  int j = i & 16383;
  int c = j >> 7, k = j & 127;
  const float* W = (m == 0) ? W0 : (m == 1) ? W1 : W2;
  Wt[i] = (_Float16)W[k * 128 + c];
}

// ---------------- fp16 MFMA GEMM + dis-scale epilogue ----------------
// hws[r][:] = dis[r] * (relu?(in[r][:]) @ W)  as fp16.

#define LDH 136   // padded halves per row -> conflict-free ds_read_b128

__global__ __launch_bounds__(256, 2)
void k_gemm(const float* __restrict__ in, int in_stride, int do_relu,
            const _Float16* __restrict__ Wt_g, const float* __restrict__ dis,
            _Float16* __restrict__ hws, int N) {
  __shared__ _Float16 Wt[128 * LDH];
  int t = threadIdx.x;
  int rbase = blockIdx.x * 128;

#pragma unroll
  for (int i = 0; i < 8; ++i) {
    int s = t + i * 256;
    int c = s >> 4, kh = s & 15;
    half8 w = ((const half8*)Wt_g)[s];
    *(half8*)&Wt[c * LDH + kh * 8] = w;
  }
  __syncthreads();

  int wv = t >> 6, lane = t & 63;
  int r0 = wv * 32;
  int lr = lane & 15, lg = lane >> 4;

  f4 acc[2][8];
#pragma unroll
  for (int fm = 0; fm < 2; ++fm)
#pragma unroll
    for (int fn = 0; fn < 8; ++fn) acc[fm][fn] = (f4){0.f, 0.f, 0.f, 0.f};

#pragma unroll
  for (int ks = 0; ks < 4; ++ks) {
    int k0 = ks * 32 + lg * 8;
    half8 a[8];
#pragma unroll
    for (int fn = 0; fn < 8; ++fn)
      a[fn] = *(const half8*)&Wt[(fn * 16 + lr) * LDH + k0];
#pragma unroll
    for (int fm = 0; fm < 2; ++fm) {
      int gr = rbase + r0 + fm * 16 + lr;
      float4 v0 = make_float4(0.f, 0.f, 0.f, 0.f);
      float4 v1 = make_float4(0.f, 0.f, 0.f, 0.f);
      if (gr < N) {
        const float* pr = in + (size_t)gr * in_stride + k0;
        v0 = *(const float4*)pr;
        v1 = *(const float4*)(pr + 4);
      }
      if (do_relu) {
        v0.x = fmaxf(v0.x, 0.f); v0.y = fmaxf(v0.y, 0.f);
        v0.z = fmaxf(v0.z, 0.f); v0.w = fmaxf(v0.w, 0.f);
        v1.x = fmaxf(v1.x, 0.f); v1.y = fmaxf(v1.y, 0.f);
        v1.z = fmaxf(v1.z, 0.f); v1.w = fmaxf(v1.w, 0.f);
      }
      half8 b;
      b[0] = (_Float16)v0.x; b[1] = (_Float16)v0.y;
      b[2] = (_Float16)v0.z; b[3] = (_Float16)v0.w;
      b[4] = (_Float16)v1.x; b[5] = (_Float16)v1.y;
      b[6] = (_Float16)v1.z; b[7] = (_Float16)v1.w;
#pragma unroll
      for (int fn = 0; fn < 8; ++fn)
        acc[fm][fn] = __builtin_amdgcn_mfma_f32_16x16x32_f16(a[fn], b, acc[fm][fn], 0, 0, 0);
    }
  }

#pragma unroll
  for (int fm = 0; fm < 2; ++fm) {
    int gr = rbase + r0 + fm * 16 + lr;
    if (gr >= N) continue;
    float dv = dis[gr];
#pragma unroll
    for (int fn = 0; fn < 8; ++fn) {
      f4 d = acc[fm][fn];
      half4 hv;
      hv[0] = (_Float16)(d[0] * dv);
      hv[1] = (_Float16)(d[1] * dv);
      hv[2] = (_Float16)(d[2] * dv);
      hv[3] = (_Float16)(d[3] * dv);
      *(half4*)(hws + (size_t)gr * 128 + fn * 16 + lg * 4) = hv;
    }
  }
}

// ---------------- aggregation: wave/node, fp16 gathers, 8-deep MLP ----------------

__global__ __launch_bounds__(256)
void k_agg(const _Float16* __restrict__ hws, const int* __restrict__ offs,
           const int* __restrict__ srcs, const float* __restrict__ dis,
           const float* __restrict__ bias, float* __restrict__ out,
           int N, int layer) {
  int wv = threadIdx.x >> 6, lane = threadIdx.x & 63;
  int v = blockIdx.x * 4 + wv;
  if (v >= N) return;

  const uint* h32 = (const uint*)hws;
  uint hv = h32[(size_t)v * 64 + lane];
  half2v h = __builtin_bit_cast(half2v, hv);
  float ax = (float)h[0], ay = (float)h[1];

  int e0 = offs[v], e1 = offs[v + 1];
  int e = e0;
  for (; e + 8 <= e1; e += 8) {
    int s0 = srcs[e + 0], s1 = srcs[e + 1], s2 = srcs[e + 2], s3 = srcs[e + 3];
    int s4 = srcs[e + 4], s5 = srcs[e + 5], s6 = srcs[e + 6], s7 = srcs[e + 7];
    uint u0 = h32[(size_t)s0 * 64 + lane];
    uint u1 = h32[(size_t)s1 * 64 + lane];
    uint u2 = h32[(size_t)s2 * 64 + lane];
    uint u3 = h32[(size_t)s3 * 64 + lane];
    uint u4 = h32[(size_t)s4 * 64 + lane];
    uint u5 = h32[(size_t)s5 * 64 + lane];
    uint u6 = h32[(size_t)s6 * 64 + lane];
    uint u7 = h32[(size_t)s7 * 64 + lane];
    half2v p0 = __builtin_bit_cast(half2v, u0);
    half2v p1 = __builtin_bit_cast(half2v, u1);
    half2v p2 = __builtin_bit_cast(half2v, u2);
    half2v p3 = __builtin_bit_cast(half2v, u3);
    half2v p4 = __builtin_bit_cast(half2v, u4);
    half2v p5 = __builtin_bit_cast(half2v, u5);
    half2v p6 = __builtin_bit_cast(half2v, u6);
    half2v p7 = __builtin_bit_cast(half2v, u7);
    ax += (float)p0[0] + (float)p1[0] + (float)p2[0] + (float)p3[0]
        + (float)p4[0] + (float)p5[0] + (float)p6[0] + (float)p7[0];
    ay += (float)p0[1] + (float)p1[1] + (float)p2[1] + (float)p3[1]
        + (float)p4[1] + (float)p5[1] + (float)p6[1] + (float)p7[1];
  }
  for (; e < e1; ++e) {
    int s = srcs[e];
    uint u = h32[(size_t)s * 64 + lane];
    half2v p = __builtin_bit_cast(half2v, u);
    ax += (float)p[0];
    ay += (float)p[1];
  }

  float dv = dis[v];
  float2 b = ((const float2*)bias)[lane];
  float2 o;
  o.x = fmaf(dv, ax, b.x);
  o.y = fmaf(dv, ay, b.y);
  *(float2*)(out + (size_t)v * 384 + layer * 128 + 2 * lane) = o;
}

// ---------------- launch ----------------

extern "C" void kernel_launch(void* const* d_in, const int* in_sizes, int n_in,
                              void* d_out, int out_size, void* d_ws, size_t ws_size,
                              hipStream_t stream) {
  const float* x  = (const float*)d_in[0];
  const int*   ei = (const int*)d_in[1];
  const float* W0 = (const float*)d_in[2];
  const float* b0 = (const float*)d_in[3];
  const float* W1 = (const float*)d_in[4];
  const float* b1 = (const float*)d_in[5];
  const float* W2 = (const float*)d_in[6];
  const float* b2 = (const float*)d_in[7];
  float* out = (float*)d_out;

  int N = in_sizes[0] / 128;
  int E = in_sizes[1] / 2;
  int nb = (N + 255) >> 8;                       // active buckets
  int chunk = (((E + NBLK - 1) / NBLK) + 255) & ~255;

  char* p = (char*)d_ws;
  auto alloc = [&](size_t sz) { char* r = p; p += (sz + 255) & ~(size_t)255; return r; };
  _Float16* hws  = (_Float16*)alloc((size_t)N * 128 * 2);
  float* dis     = (float*)alloc((size_t)N * 4);
  int*   offs    = (int*)alloc((size_t)(N + 1) * 4);
  int*   srcs    = (int*)alloc((size_t)E * 4);
  _Float16* Wt   = (_Float16*)alloc((size_t)3 * 128 * 128 * 2);
  int*   hb      = (int*)alloc((size_t)2 * NBLK * NBK * 4);
  int*   totals  = (int*)alloc((size_t)2 * NBK * 4);
  int*   boffs   = (int*)alloc((size_t)(NBK + 1) * 4);
  int*   soffs   = (int*)alloc((size_t)(NBK + 1) * 4);
  unsigned long long* pairs = (unsigned long long*)alloc((size_t)E * 8);
  unsigned char* srcb = (unsigned char*)alloc((size_t)E);

  k_bhist<<<NBLK, 256, 0, stream>>>(ei, E, chunk, hb);
  k_colscan<<<8, 256, 0, stream>>>(hb, totals);
  k_bscan2<<<1, 1024, 0, stream>>>(totals, boffs, soffs, offs, N, E);
  k_bscatter<<<NBLK, 256, 0, stream>>>(ei, E, chunk, hb, boffs, soffs, pairs, srcb);
  k_deg<<<nb, 256, 0, stream>>>(srcb, soffs, dis, N);
  k_fscatter<<<nb, 256, 0, stream>>>(pairs, boffs, offs, srcs, N);
  k_prepw<<<192, 256, 0, stream>>>(W0, W1, W2, Wt);

  int gG = (N + 127) / 128;
  int gA = (N + 3) / 4;

  // layer 0
  k_gemm<<<gG, 256, 0, stream>>>(x, 128, 0, Wt, dis, hws, N);
  k_agg<<<gA, 256, 0, stream>>>(hws, offs, srcs, dis, b0, out, N, 0);
  // layer 1: input = relu(out[:,0,:]) (stride 384)
  k_gemm<<<gG, 256, 0, stream>>>(out, 384, 1, Wt + 16384, dis, hws, N);
  k_agg<<<gA, 256, 0, stream>>>(hws, offs, srcs, dis, b1, out, N, 1);
  // layer 2: input = relu(out[:,1,:])
  k_gemm<<<gG, 256, 0, stream>>>(out + 128, 384, 1, Wt + 32768, dis, hws, N);
  k_agg<<<gA, 256, 0, stream>>>(hws, offs, srcs, dis, b2, out, N, 2);
}